// Round 5
// baseline (268.798 us; speedup 1.0000x reference)
//
#include <hip/hip_runtime.h>
#include <cfloat>

typedef unsigned short u16;
typedef unsigned int   u32;
typedef __attribute__((ext_vector_type(8))) short short8;
typedef __attribute__((ext_vector_type(4))) float float4_;
typedef __attribute__((ext_vector_type(2))) float float2_;

#define NB   2
#define N1   4096
#define N2   32768
#define C1   128
#define C2   64
#define CIN  192      // C1 + C2
#define F1   128
#define F2   128
#define ROW0 131      // 3 + C1 (fp32)
#define ROW1 67       // 3 + C2 (fp32)
#define NQ   (NB * N2)   // 65536 total query points
#define EPSF 1e-07f
#define KSPLIT 8
#define KCH  (N1 / KSPLIT)   // 512 candidates per tile
#define PADX 200      // LDS x-tile pitch (u16)
#define PADH 136      // LDS h-tile pitch (u16)

// round-to-nearest-even fp32 -> bf16 (finite data only)
__device__ __forceinline__ u16 f2bf(float f) {
  u32 x = __float_as_uint(f);
  return (u16)((x + 0x7fffu + ((x >> 16) & 1u)) >> 16);
}

// BRANCHLESS stable top-3 insert (merge path only). Strict <: earlier index wins.
__device__ __forceinline__ void ins3b(float d, int gi,
    float& d0, float& d1, float& d2, int& i0, int& i1, int& i2) {
  bool lt0 = d < d0, lt1 = d < d1, lt2 = d < d2;
  d2 = lt1 ? d1 : (lt2 ? d : d2);
  i2 = lt1 ? i1 : (lt2 ? gi : i2);
  d1 = lt0 ? d0 : (lt1 ? d : d1);
  i1 = lt0 ? i0 : (lt1 ? gi : i1);
  d0 = lt0 ? d : d0;
  i0 = lt0 ? gi : i0;
}

struct Part { float d0, d1, d2; int i0, i1, i2; };   // 24 B
struct KW   { int i0, i1, i2; float w0, w1, w2; };   // 24 B

// ---- repack: weights fp32 -> transposed bf16; candidates -> NEGATED SoA quads --
// xyz1q layout: per batch, per group g of 4 candidates: float4 X=(-x0,-x1,-x2,-x3),
// float4 Y, float4 Z consecutive (48 B / group). Negation is exact, so
// q + (-c) == q - c bitwise; SoA pairs feed v_pk_* SGPR-pair operands directly.
__global__ void repack_w(const float* __restrict__ W1, const float* __restrict__ W2,
                         u16* __restrict__ W1t, u16* __restrict__ W2t,
                         const float* __restrict__ in0, float* __restrict__ xyz1q) {
  int i = blockIdx.x * 256 + threadIdx.x;
  if (i < F1 * CIN) { int n = i / CIN, k = i % CIN; W1t[i] = f2bf(W1[k * F1 + n]); }
  if (i < F2 * F1)  { int n = i / F1,  k = i % F1;  W2t[i] = f2bf(W2[k * F2 + n]); }
  if (i < NB * N1)  {
    const float* r = in0 + (size_t)i * ROW0;
    int b = i >> 12;                 // i / N1
    int g = (i & (N1 - 1)) >> 2, s = i & 3;
    float* dst = xyz1q + ((size_t)(b * (N1 / 4) + g)) * 12;
    dst[s]     = -r[0];
    dst[4 + s] = -r[1];
    dst[8 + s] = -r[2];
  }
}

// ---- K1: kNN partial top-3, packed-fp32 distance math --------------------------
// grid (NQ/256, KSPLIT) = 2048 blocks -> 8 blocks/CU, 32 waves/CU.
// Issue-bound kernel (R4: 21 VALU/candidate = measured floor). v_pk_add/mul_f32
// process 2 candidates/slot for the distance part: per 4 candidates
// 16 pk + 4x11 insert + 4 gi-movs = 16.25 slots/candidate (-24%).
// Distances bit-identical: pk halves are IEEE RN fp32, order (dx^2+dy^2)+dz^2.
__global__ __launch_bounds__(256) void knn_part(const float* __restrict__ xyz1q,
                                                const float* __restrict__ in1,
                                                Part* __restrict__ part,
                                                float* __restrict__ out) {
  int t = threadIdx.x;
  int bb = blockIdx.x >> 7;                   // batch: uniform, threadIdx-free
  int ct = blockIdx.y;
  int c0 = ct * KCH;
  const float4* __restrict__ srcq =
      (const float4*)(xyz1q + ((size_t)(bb * (N1 / 4) + (c0 >> 2))) * 12);
  int q = blockIdx.x * 256 + t;
  int n = q & (N2 - 1);
  const float* qr = in1 + (size_t)(bb * N2 + n) * ROW1;
  float qx = qr[0], qy = qr[1], qz = qr[2];
  if (ct == 0) {                              // xyz2 passthrough (was xyz_copy)
    float* o = out + (size_t)NQ * F2 + (size_t)q * 3;
    o[0] = qx; o[1] = qy; o[2] = qz;
  }
  float2_ qxp = {qx, qx}, qyp = {qy, qy}, qzp = {qz, qz};
  float d0 = FLT_MAX, d1 = FLT_MAX, d2 = FLT_MAX;
  int   i0 = 0, i1 = 0, i2 = 0;
#pragma unroll 4
  for (int g = 0; g < KCH / 4; g++) {
    float4 X = srcq[3 * g + 0];               // uniform -> s_load_dwordx4
    float4 Y = srcq[3 * g + 1];
    float4 Z = srcq[3 * g + 2];
    float2_ x01 = {X.x, X.y}, x23 = {X.z, X.w};
    float2_ y01 = {Y.x, Y.y}, y23 = {Y.z, Y.w};
    float2_ z01 = {Z.x, Z.y}, z23 = {Z.z, Z.w};
    float2_ dA, dB, t0, t1, t2, t3, t4, t5;
    // 16 pk-ops -> 4 distances (dA = d[g4+0], d[g4+1]; dB = d[g4+2], d[g4+3])
    asm("v_pk_add_f32 %[t0], %[qx], %[x01]\n\t"   // dx = qx + (-cx)
        "v_pk_add_f32 %[t1], %[qx], %[x23]\n\t"
        "v_pk_add_f32 %[t2], %[qy], %[y01]\n\t"
        "v_pk_add_f32 %[t3], %[qy], %[y23]\n\t"
        "v_pk_add_f32 %[t4], %[qz], %[z01]\n\t"
        "v_pk_add_f32 %[t5], %[qz], %[z23]\n\t"
        "v_pk_mul_f32 %[t0], %[t0], %[t0]\n\t"
        "v_pk_mul_f32 %[t1], %[t1], %[t1]\n\t"
        "v_pk_mul_f32 %[t2], %[t2], %[t2]\n\t"
        "v_pk_mul_f32 %[t3], %[t3], %[t3]\n\t"
        "v_pk_mul_f32 %[t4], %[t4], %[t4]\n\t"
        "v_pk_mul_f32 %[t5], %[t5], %[t5]\n\t"
        "v_pk_add_f32 %[t0], %[t0], %[t2]\n\t"    // dx^2 + dy^2
        "v_pk_add_f32 %[t1], %[t1], %[t3]\n\t"
        "v_pk_add_f32 %[dA], %[t0], %[t4]\n\t"    // + dz^2 (exact ref order)
        "v_pk_add_f32 %[dB], %[t1], %[t5]"
        : [dA]"=v"(dA), [dB]"=v"(dB),
          [t0]"=&v"(t0), [t1]"=&v"(t1), [t2]"=&v"(t2),
          [t3]"=&v"(t3), [t4]"=&v"(t4), [t5]"=&v"(t5)
        : [qx]"v"(qxp), [qy]"v"(qyp), [qz]"v"(qzp),
          [x01]"s"(x01), [x23]"s"(x23), [y01]"s"(y01),
          [y23]"s"(y23), [z01]"s"(z01), [z23]"s"(z23));
    float ds[4] = {dA.x, dA.y, dB.x, dB.y};
#pragma unroll
    for (int k = 0; k < 4; k++) {             // ascending index: tie-stable
      float vd = ds[k];
      int gi = c0 + 4 * g + k;                // "v" constraint -> v_mov
      int tm;
      asm("v_cmp_nlt_f32 vcc, %[vd], %[d2]\n\t"       // vcc = !(d<d2)
          "v_cndmask_b32 %[tm], %[gi], %[i2], vcc\n\t"  // t2 = lt2 ? gi : i2
          "v_cmp_nlt_f32 vcc, %[vd], %[d1]\n\t"
          "v_cndmask_b32 %[i2], %[i1], %[tm], vcc\n\t"  // i2 = lt1 ? i1 : t2
          "v_cndmask_b32 %[tm], %[gi], %[i1], vcc\n\t"  // t1 = lt1 ? gi : i1
          "v_cmp_nlt_f32 vcc, %[vd], %[d0]\n\t"
          "v_cndmask_b32 %[i1], %[i0], %[tm], vcc\n\t"  // i1 = lt0 ? i0 : t1
          "v_cndmask_b32 %[i0], %[gi], %[i0], vcc\n\t"  // i0 = lt0 ? gi : i0
          "v_med3_f32 %[d2], %[vd], %[d1], %[d2]\n\t"   // value sorting network
          "v_med3_f32 %[d1], %[d0], %[vd], %[d1]\n\t"
          "v_min_f32 %[d0], %[vd], %[d0]"
          : [d0]"+v"(d0), [d1]"+v"(d1), [d2]"+v"(d2),
            [i0]"+v"(i0), [i1]"+v"(i1), [i2]"+v"(i2), [tm]"=&v"(tm)
          : [vd]"v"(vd), [gi]"v"(gi)
          : "vcc");
    }
  }
  Part p; p.d0 = d0; p.d1 = d1; p.d2 = d2; p.i0 = i0; p.i1 = i1; p.i2 = i2;
  part[((size_t)q << 3) + ct] = p;
}

// ---- K2: merge partials (ascending tile order preserves tie stability) ---------
__global__ __launch_bounds__(256) void knn_merge(const Part* __restrict__ part,
                                                 KW* __restrict__ kw) {
  int q = blockIdx.x * 256 + threadIdx.x;
  float d0 = FLT_MAX, d1 = FLT_MAX, d2 = FLT_MAX;
  int   i0 = 0, i1 = 0, i2 = 0;
#pragma unroll
  for (int ct = 0; ct < KSPLIT; ct++) {
    Part p = part[((size_t)q << 3) + ct];
    ins3b(p.d0, p.i0, d0, d1, d2, i0, i1, i2);
    ins3b(p.d1, p.i1, d0, d1, d2, i0, i1, i2);
    ins3b(p.d2, p.i2, d0, d1, d2, i0, i1, i2);
  }
  float a0 = fmaxf(d0, EPSF), a1 = fmaxf(d1, EPSF), a2 = fmaxf(d2, EPSF);
  float w0 = 1.f / a0, w1 = 1.f / a1, w2 = 1.f / a2;
  float s = __fadd_rn(__fadd_rn(w0, w1), w2);
  KW o; o.i0 = i0; o.i1 = i1; o.i2 = i2;
  o.w0 = w0 / s; o.w1 = w1 / s; o.w2 = w2 / s;
  kw[q] = o;
}

// ---- K3: interp + concat -> bf16 LDS -> MFMA MLP1 -> MFMA MLP2 -> fp32 out -----
// block = 256 = 4 waves; each wave owns 16 query rows. 1024 blocks.
__global__ __launch_bounds__(256) void interp_mlp(
    const float* __restrict__ in0, const float* __restrict__ in1,
    const KW* __restrict__ kw,
    const u16* __restrict__ W1t, const float* __restrict__ b1,
    const u16* __restrict__ W2t, const float* __restrict__ b2,
    float* __restrict__ out) {
  __shared__ __align__(16) u16 xs[4][16][PADX];   // 25,600 B
  __shared__ __align__(16) u16 hs[4][16][PADH];   // 17,408 B
  int t = threadIdx.x;
  int wave = t >> 6, lane = t & 63;
  int l16 = lane & 15, quad = lane >> 4;
  int qbase = blockIdx.x * 64 + wave * 16;
  int b = qbase >> 15;                  // uniform per block

  // interp + concat into xs[wave] (16 x 192), fp32 gather, bf16 pack
  for (int qi = 0; qi < 16; qi++) {
    int q = qbase + qi;
    KW k = kw[q];                       // wave-uniform load
    const float* base = in0 + (size_t)b * N1 * ROW0 + 3;
    const float* r0 = base + (size_t)k.i0 * ROW0;
    const float* r1 = base + (size_t)k.i1 * ROW0;
    const float* r2 = base + (size_t)k.i2 * ROW0;
    float lo = __fadd_rn(__fadd_rn(__fmul_rn(k.w0, r0[lane]),
                                   __fmul_rn(k.w1, r1[lane])),
                         __fmul_rn(k.w2, r2[lane]));
    float hi = __fadd_rn(__fadd_rn(__fmul_rn(k.w0, r0[64 + lane]),
                                   __fmul_rn(k.w1, r1[64 + lane])),
                         __fmul_rn(k.w2, r2[64 + lane]));
    xs[wave][qi][lane]      = f2bf(lo);
    xs[wave][qi][64 + lane] = f2bf(hi);
    int n2 = q & (N2 - 1);              // channels 128..191 = points2
    xs[wave][qi][C1 + lane] = f2bf(in1[(size_t)(b * N2 + n2) * ROW1 + 3 + lane]);
  }
  __syncthreads();

  // GEMM1: h = relu(x @ W1 + b1); A from LDS, B from global (L1/L2-resident)
  float4_ acc[8];
#pragma unroll
  for (int nt = 0; nt < 8; nt++) acc[nt] = (float4_)0.f;
#pragma unroll
  for (int k0 = 0; k0 < CIN; k0 += 32) {
    short8 af = *(const short8*)&xs[wave][l16][k0 + quad * 8];
#pragma unroll
    for (int nt = 0; nt < 8; nt++) {
      short8 bf = *(const short8*)(W1t + (size_t)(nt * 16 + l16) * CIN + k0 + quad * 8);
      acc[nt] = __builtin_amdgcn_mfma_f32_16x16x32_bf16(af, bf, acc[nt], 0, 0, 0);
    }
  }
#pragma unroll
  for (int nt = 0; nt < 8; nt++) {
    float bv = b1[nt * 16 + l16];
#pragma unroll
    for (int r = 0; r < 4; r++) {   // C/D: row=quad*4+r, col=nt*16+l16
      hs[wave][quad * 4 + r][nt * 16 + l16] = f2bf(fmaxf(acc[nt][r] + bv, 0.f));
    }
  }
  __syncthreads();

  // GEMM2: y = relu(h @ W2 + b2) -> fp32 global store
  float4_ a2[8];
#pragma unroll
  for (int nt = 0; nt < 8; nt++) a2[nt] = (float4_)0.f;
#pragma unroll
  for (int k0 = 0; k0 < F1; k0 += 32) {
    short8 af = *(const short8*)&hs[wave][l16][k0 + quad * 8];
#pragma unroll
    for (int nt = 0; nt < 8; nt++) {
      short8 bf = *(const short8*)(W2t + (size_t)(nt * 16 + l16) * F1 + k0 + quad * 8);
      a2[nt] = __builtin_amdgcn_mfma_f32_16x16x32_bf16(af, bf, a2[nt], 0, 0, 0);
    }
  }
#pragma unroll
  for (int nt = 0; nt < 8; nt++) {
    float bv = b2[nt * 16 + l16];
#pragma unroll
    for (int r = 0; r < 4; r++) {
      int row = qbase + quad * 4 + r;
      out[(size_t)row * F2 + nt * 16 + l16] = fmaxf(a2[nt][r] + bv, 0.f);
    }
  }
}

extern "C" void kernel_launch(void* const* d_in, const int* in_sizes, int n_in,
                              void* d_out, int out_size, void* d_ws, size_t ws_size,
                              hipStream_t stream) {
  // input assignment by element count (ordering-invariant); positional fallback
  const float *in0 = nullptr, *in1 = nullptr, *W1 = nullptr, *W2 = nullptr;
  const float *b1 = nullptr, *b2 = nullptr;
  for (int i = 0; i < n_in; i++) {
    const float* p = (const float*)d_in[i];
    switch (in_sizes[i]) {
      case 2 * N1 * ROW0: in0 = p; break;
      case 2 * N2 * ROW1: in1 = p; break;
      case CIN * F1:      W1  = p; break;
      case F1 * F2:       W2  = p; break;
      case F1:            (b1 ? b2 : b1) = p; break;
      default: break;
    }
  }
  if (!in0) in0 = (const float*)d_in[0];
  if (!in1) in1 = (const float*)d_in[1];
  if (!W1)  W1  = (const float*)d_in[2];
  if (!b1)  b1  = (const float*)d_in[3];
  if (!W2)  W2  = (const float*)d_in[4];
  if (!b2)  b2  = (const float*)d_in[5];

  float* out = (float*)d_out;   // fp32: x (65536*128) ++ xyz2 (65536*3)

  // ws (13.58 MiB, proven size): W1t 49,152 | W2t 32,768 | kw 1,572,864 | part 12,582,912
  // xyz1q (98,304) ALIASES the kw region: repack writes it each iteration,
  // knn_part reads it, then knn_merge overwrites the region with kw (xyz1q dead).
  char* ws = (char*)d_ws;
  u16*    W1t   = (u16*)(ws + 0);
  u16*    W2t   = (u16*)(ws + 49152);
  float*  xyz1q = (float*)(ws + 81920);       // alias of kw region
  KW*     kw    = (KW*)(ws + 81920);
  Part*   part  = (Part*)(ws + 1654784);

  repack_w<<<dim3(96), dim3(256), 0, stream>>>(W1, W2, W1t, W2t, in0, xyz1q);
  knn_part<<<dim3(NQ / 256, KSPLIT), dim3(256), 0, stream>>>(xyz1q, in1, part, out);
  knn_merge<<<dim3(NQ / 256), dim3(256), 0, stream>>>(part, kw);
  interp_mlp<<<dim3(NQ / 64), dim3(256), 0, stream>>>(in0, in1, kw, W1t, b1, W2t, b2, out);
}

// Round 6
// 258.255 us; speedup vs baseline: 1.0408x; 1.0408x over previous
//
#include <hip/hip_runtime.h>
#include <cfloat>

typedef unsigned short u16;
typedef unsigned int   u32;
typedef __attribute__((ext_vector_type(8))) short short8;
typedef __attribute__((ext_vector_type(4))) float float4_;
typedef __attribute__((ext_vector_type(2))) float float2_;

#define NB   2
#define N1   4096
#define N2   32768
#define C1   128
#define C2   64
#define CIN  192      // C1 + C2
#define F1   128
#define F2   128
#define ROW0 131      // 3 + C1 (fp32)
#define ROW1 67       // 3 + C2 (fp32)
#define NQ   (NB * N2)   // 65536 total query points
#define EPSF 1e-07f
#define KSPLIT 8
#define KCH  (N1 / KSPLIT)   // 512 candidates per tile
#define NGRP (KCH / 4)       // 128 groups of 4 candidates
#define PADX 200      // LDS x-tile pitch (u16)
#define PADH 136      // LDS h-tile pitch (u16)

// round-to-nearest-even fp32 -> bf16 (finite data only)
__device__ __forceinline__ u16 f2bf(float f) {
  u32 x = __float_as_uint(f);
  return (u16)((x + 0x7fffu + ((x >> 16) & 1u)) >> 16);
}

// BRANCHLESS stable top-3 insert (merge path only). Strict <: earlier index wins.
__device__ __forceinline__ void ins3b(float d, int gi,
    float& d0, float& d1, float& d2, int& i0, int& i1, int& i2) {
  bool lt0 = d < d0, lt1 = d < d1, lt2 = d < d2;
  d2 = lt1 ? d1 : (lt2 ? d : d2);
  i2 = lt1 ? i1 : (lt2 ? gi : i2);
  d1 = lt0 ? d0 : (lt1 ? d : d1);
  i1 = lt0 ? i0 : (lt1 ? gi : i1);
  d0 = lt0 ? d : d0;
  i0 = lt0 ? gi : i0;
}

// proven R4 insert block: 3 cmp_nlt + 5 cndmask (all-VGPR+vcc) + min/med3 net.
__device__ __forceinline__ void ins3asm(float vd, int gi,
    float& d0, float& d1, float& d2, int& i0, int& i1, int& i2) {
  int tm;
  asm("v_cmp_nlt_f32 vcc, %[vd], %[d2]\n\t"         // vcc = !(d<d2)
      "v_cndmask_b32 %[tm], %[gi], %[i2], vcc\n\t"  // t2 = lt2 ? gi : i2
      "v_cmp_nlt_f32 vcc, %[vd], %[d1]\n\t"
      "v_cndmask_b32 %[i2], %[i1], %[tm], vcc\n\t"  // i2 = lt1 ? i1 : t2
      "v_cndmask_b32 %[tm], %[gi], %[i1], vcc\n\t"  // t1 = lt1 ? gi : i1
      "v_cmp_nlt_f32 vcc, %[vd], %[d0]\n\t"
      "v_cndmask_b32 %[i1], %[i0], %[tm], vcc\n\t"  // i1 = lt0 ? i0 : t1
      "v_cndmask_b32 %[i0], %[gi], %[i0], vcc\n\t"  // i0 = lt0 ? gi : i0
      "v_med3_f32 %[d2], %[vd], %[d1], %[d2]\n\t"   // value sorting network
      "v_med3_f32 %[d1], %[d0], %[vd], %[d1]\n\t"
      "v_min_f32 %[d0], %[vd], %[d0]"
      : [d0]"+v"(d0), [d1]"+v"(d1), [d2]"+v"(d2),
        [i0]"+v"(i0), [i1]"+v"(i1), [i2]"+v"(i2), [tm]"=&v"(tm)
      : [vd]"v"(vd), [gi]"v"(gi)
      : "vcc");
}

struct Part { float d0, d1, d2; int i0, i1, i2; };   // 24 B
struct KW   { int i0, i1, i2; float w0, w1, w2; };   // 24 B

// ---- repack: weights fp32 -> transposed bf16; candidates -> NEGATED SoA quads --
// xyz1q layout: per batch, per group g of 4 candidates: float4 X=(-x0,-x1,-x2,-x3),
// float4 Y, float4 Z consecutive (48 B / group). Negation is exact, so
// q + (-c) == q - c bitwise.
__global__ void repack_w(const float* __restrict__ W1, const float* __restrict__ W2,
                         u16* __restrict__ W1t, u16* __restrict__ W2t,
                         const float* __restrict__ in0, float* __restrict__ xyz1q) {
  int i = blockIdx.x * 256 + threadIdx.x;
  if (i < F1 * CIN) { int n = i / CIN, k = i % CIN; W1t[i] = f2bf(W1[k * F1 + n]); }
  if (i < F2 * F1)  { int n = i / F1,  k = i % F1;  W2t[i] = f2bf(W2[k * F2 + n]); }
  if (i < NB * N1)  {
    const float* r = in0 + (size_t)i * ROW0;
    int b = i >> 12;                 // i / N1
    int g = (i & (N1 - 1)) >> 2, s = i & 3;
    float* dst = xyz1q + ((size_t)(b * (N1 / 4) + g)) * 12;
    dst[s]     = -r[0];
    dst[4 + s] = -r[1];
    dst[8 + s] = -r[2];
  }
}

// ---- K1: kNN partial top-3, pk-fp32 distance, LDS-broadcast candidates ---------
// grid (NQ/256, KSPLIT) = 2048 blocks -> 8 blocks/CU target, 6 KB LDS/block.
// R5 lesson: SGPR-fed pk asm stalls on lgkmcnt (VALUBusy 115->81). Fix: tile in
// LDS (6 KB SoA), 3x ds_read_b128/group (same addr all lanes -> broadcast, DS
// pipe, zero VALU slots), pk math all-VGPR in a small asm block so the compiler
// can interleave ds_reads with fine-grained lgkmcnt across groups.
// Budget per 4 candidates: 16 pk + 4x11 insert + 4 gi-movs = 64 VALU = 16/cand
// (R4 floor was 21/cand at 124 us). Distances bit-identical to reference.
__global__ __launch_bounds__(256) void knn_part(const float* __restrict__ xyz1q,
                                                const float* __restrict__ in1,
                                                Part* __restrict__ part,
                                                float* __restrict__ out) {
  __shared__ __align__(16) float4 cs4[NGRP * 3];   // 6144 B
  int t = threadIdx.x;
  int bb = blockIdx.x >> 7;                   // batch: uniform, threadIdx-free
  int ct = blockIdx.y;
  int c0 = ct * KCH;
  const float4* __restrict__ srcq =
      (const float4*)xyz1q + ((size_t)(bb * (N1 / 4) + (c0 >> 2))) * 3;
  for (int j = t; j < NGRP * 3; j += 256) cs4[j] = srcq[j];
  int q = blockIdx.x * 256 + t;
  int n = q & (N2 - 1);
  const float* qr = in1 + (size_t)(bb * N2 + n) * ROW1;
  float qx = qr[0], qy = qr[1], qz = qr[2];
  if (ct == 0) {                              // xyz2 passthrough (was xyz_copy)
    float* o = out + (size_t)NQ * F2 + (size_t)q * 3;
    o[0] = qx; o[1] = qy; o[2] = qz;
  }
  __syncthreads();
  float2_ qxp = {qx, qx}, qyp = {qy, qy}, qzp = {qz, qz};
  float d0 = FLT_MAX, d1 = FLT_MAX, d2 = FLT_MAX;
  int   i0 = 0, i1 = 0, i2 = 0;
#pragma unroll 2
  for (int g = 0; g < NGRP; g++) {
    float4 X = cs4[3 * g + 0];                // ds_read_b128, lane-uniform addr
    float4 Y = cs4[3 * g + 1];
    float4 Z = cs4[3 * g + 2];
    float2_ x01 = {X.x, X.y}, x23 = {X.z, X.w};
    float2_ y01 = {Y.x, Y.y}, y23 = {Y.z, Y.w};
    float2_ z01 = {Z.x, Z.y}, z23 = {Z.z, Z.w};
    float2_ dA, dB, t0, t1, t2, t3, t4, t5;
    // 16 pk-ops -> 4 distances; all-VGPR (no const-bus, no SGPR pressure)
    asm("v_pk_add_f32 %[t0], %[qx], %[x01]\n\t"   // dx = qx + (-cx)
        "v_pk_add_f32 %[t1], %[qx], %[x23]\n\t"
        "v_pk_add_f32 %[t2], %[qy], %[y01]\n\t"
        "v_pk_add_f32 %[t3], %[qy], %[y23]\n\t"
        "v_pk_add_f32 %[t4], %[qz], %[z01]\n\t"
        "v_pk_add_f32 %[t5], %[qz], %[z23]\n\t"
        "v_pk_mul_f32 %[t0], %[t0], %[t0]\n\t"
        "v_pk_mul_f32 %[t1], %[t1], %[t1]\n\t"
        "v_pk_mul_f32 %[t2], %[t2], %[t2]\n\t"
        "v_pk_mul_f32 %[t3], %[t3], %[t3]\n\t"
        "v_pk_mul_f32 %[t4], %[t4], %[t4]\n\t"
        "v_pk_mul_f32 %[t5], %[t5], %[t5]\n\t"
        "v_pk_add_f32 %[t0], %[t0], %[t2]\n\t"    // dx^2 + dy^2
        "v_pk_add_f32 %[t1], %[t1], %[t3]\n\t"
        "v_pk_add_f32 %[dA], %[t0], %[t4]\n\t"    // + dz^2 (exact ref order)
        "v_pk_add_f32 %[dB], %[t1], %[t5]"
        : [dA]"=&v"(dA), [dB]"=&v"(dB),
          [t0]"=&v"(t0), [t1]"=&v"(t1), [t2]"=&v"(t2),
          [t3]"=&v"(t3), [t4]"=&v"(t4), [t5]"=&v"(t5)
        : [qx]"v"(qxp), [qy]"v"(qyp), [qz]"v"(qzp),
          [x01]"v"(x01), [x23]"v"(x23), [y01]"v"(y01),
          [y23]"v"(y23), [z01]"v"(z01), [z23]"v"(z23));
    int gb = c0 + 4 * g;
    ins3asm(dA.x, gb + 0, d0, d1, d2, i0, i1, i2);  // ascending: tie-stable
    ins3asm(dA.y, gb + 1, d0, d1, d2, i0, i1, i2);
    ins3asm(dB.x, gb + 2, d0, d1, d2, i0, i1, i2);
    ins3asm(dB.y, gb + 3, d0, d1, d2, i0, i1, i2);
  }
  Part p; p.d0 = d0; p.d1 = d1; p.d2 = d2; p.i0 = i0; p.i1 = i1; p.i2 = i2;
  part[((size_t)q << 3) + ct] = p;
}

// ---- K2: merge partials (ascending tile order preserves tie stability) ---------
__global__ __launch_bounds__(256) void knn_merge(const Part* __restrict__ part,
                                                 KW* __restrict__ kw) {
  int q = blockIdx.x * 256 + threadIdx.x;
  float d0 = FLT_MAX, d1 = FLT_MAX, d2 = FLT_MAX;
  int   i0 = 0, i1 = 0, i2 = 0;
#pragma unroll
  for (int ct = 0; ct < KSPLIT; ct++) {
    Part p = part[((size_t)q << 3) + ct];
    ins3b(p.d0, p.i0, d0, d1, d2, i0, i1, i2);
    ins3b(p.d1, p.i1, d0, d1, d2, i0, i1, i2);
    ins3b(p.d2, p.i2, d0, d1, d2, i0, i1, i2);
  }
  float a0 = fmaxf(d0, EPSF), a1 = fmaxf(d1, EPSF), a2 = fmaxf(d2, EPSF);
  float w0 = 1.f / a0, w1 = 1.f / a1, w2 = 1.f / a2;
  float s = __fadd_rn(__fadd_rn(w0, w1), w2);
  KW o; o.i0 = i0; o.i1 = i1; o.i2 = i2;
  o.w0 = w0 / s; o.w1 = w1 / s; o.w2 = w2 / s;
  kw[q] = o;
}

// ---- K3: interp + concat -> bf16 LDS -> MFMA MLP1 -> MFMA MLP2 -> fp32 out -----
// block = 256 = 4 waves; each wave owns 16 query rows. 1024 blocks.
__global__ __launch_bounds__(256) void interp_mlp(
    const float* __restrict__ in0, const float* __restrict__ in1,
    const KW* __restrict__ kw,
    const u16* __restrict__ W1t, const float* __restrict__ b1,
    const u16* __restrict__ W2t, const float* __restrict__ b2,
    float* __restrict__ out) {
  __shared__ __align__(16) u16 xs[4][16][PADX];   // 25,600 B
  __shared__ __align__(16) u16 hs[4][16][PADH];   // 17,408 B
  int t = threadIdx.x;
  int wave = t >> 6, lane = t & 63;
  int l16 = lane & 15, quad = lane >> 4;
  int qbase = blockIdx.x * 64 + wave * 16;
  int b = qbase >> 15;                  // uniform per block

  // interp + concat into xs[wave] (16 x 192), fp32 gather, bf16 pack
  for (int qi = 0; qi < 16; qi++) {
    int q = qbase + qi;
    KW k = kw[q];                       // wave-uniform load
    const float* base = in0 + (size_t)b * N1 * ROW0 + 3;
    const float* r0 = base + (size_t)k.i0 * ROW0;
    const float* r1 = base + (size_t)k.i1 * ROW0;
    const float* r2 = base + (size_t)k.i2 * ROW0;
    float lo = __fadd_rn(__fadd_rn(__fmul_rn(k.w0, r0[lane]),
                                   __fmul_rn(k.w1, r1[lane])),
                         __fmul_rn(k.w2, r2[lane]));
    float hi = __fadd_rn(__fadd_rn(__fmul_rn(k.w0, r0[64 + lane]),
                                   __fmul_rn(k.w1, r1[64 + lane])),
                         __fmul_rn(k.w2, r2[64 + lane]));
    xs[wave][qi][lane]      = f2bf(lo);
    xs[wave][qi][64 + lane] = f2bf(hi);
    int n2 = q & (N2 - 1);              // channels 128..191 = points2
    xs[wave][qi][C1 + lane] = f2bf(in1[(size_t)(b * N2 + n2) * ROW1 + 3 + lane]);
  }
  __syncthreads();

  // GEMM1: h = relu(x @ W1 + b1); A from LDS, B from global (L1/L2-resident)
  float4_ acc[8];
#pragma unroll
  for (int nt = 0; nt < 8; nt++) acc[nt] = (float4_)0.f;
#pragma unroll
  for (int k0 = 0; k0 < CIN; k0 += 32) {
    short8 af = *(const short8*)&xs[wave][l16][k0 + quad * 8];
#pragma unroll
    for (int nt = 0; nt < 8; nt++) {
      short8 bf = *(const short8*)(W1t + (size_t)(nt * 16 + l16) * CIN + k0 + quad * 8);
      acc[nt] = __builtin_amdgcn_mfma_f32_16x16x32_bf16(af, bf, acc[nt], 0, 0, 0);
    }
  }
#pragma unroll
  for (int nt = 0; nt < 8; nt++) {
    float bv = b1[nt * 16 + l16];
#pragma unroll
    for (int r = 0; r < 4; r++) {   // C/D: row=quad*4+r, col=nt*16+l16
      hs[wave][quad * 4 + r][nt * 16 + l16] = f2bf(fmaxf(acc[nt][r] + bv, 0.f));
    }
  }
  __syncthreads();

  // GEMM2: y = relu(h @ W2 + b2) -> fp32 global store
  float4_ a2[8];
#pragma unroll
  for (int nt = 0; nt < 8; nt++) a2[nt] = (float4_)0.f;
#pragma unroll
  for (int k0 = 0; k0 < F1; k0 += 32) {
    short8 af = *(const short8*)&hs[wave][l16][k0 + quad * 8];
#pragma unroll
    for (int nt = 0; nt < 8; nt++) {
      short8 bf = *(const short8*)(W2t + (size_t)(nt * 16 + l16) * F1 + k0 + quad * 8);
      a2[nt] = __builtin_amdgcn_mfma_f32_16x16x32_bf16(af, bf, a2[nt], 0, 0, 0);
    }
  }
#pragma unroll
  for (int nt = 0; nt < 8; nt++) {
    float bv = b2[nt * 16 + l16];
#pragma unroll
    for (int r = 0; r < 4; r++) {
      int row = qbase + quad * 4 + r;
      out[(size_t)row * F2 + nt * 16 + l16] = fmaxf(a2[nt][r] + bv, 0.f);
    }
  }
}

extern "C" void kernel_launch(void* const* d_in, const int* in_sizes, int n_in,
                              void* d_out, int out_size, void* d_ws, size_t ws_size,
                              hipStream_t stream) {
  // input assignment by element count (ordering-invariant); positional fallback
  const float *in0 = nullptr, *in1 = nullptr, *W1 = nullptr, *W2 = nullptr;
  const float *b1 = nullptr, *b2 = nullptr;
  for (int i = 0; i < n_in; i++) {
    const float* p = (const float*)d_in[i];
    switch (in_sizes[i]) {
      case 2 * N1 * ROW0: in0 = p; break;
      case 2 * N2 * ROW1: in1 = p; break;
      case CIN * F1:      W1  = p; break;
      case F1 * F2:       W2  = p; break;
      case F1:            (b1 ? b2 : b1) = p; break;
      default: break;
    }
  }
  if (!in0) in0 = (const float*)d_in[0];
  if (!in1) in1 = (const float*)d_in[1];
  if (!W1)  W1  = (const float*)d_in[2];
  if (!b1)  b1  = (const float*)d_in[3];
  if (!W2)  W2  = (const float*)d_in[4];
  if (!b2)  b2  = (const float*)d_in[5];

  float* out = (float*)d_out;   // fp32: x (65536*128) ++ xyz2 (65536*3)

  // ws (13.58 MiB, proven size): W1t 49,152 | W2t 32,768 | kw 1,572,864 | part 12,582,912
  // xyz1q (98,304) ALIASES the kw region: repack writes it each iteration,
  // knn_part reads it, then knn_merge overwrites the region with kw (xyz1q dead).
  char* ws = (char*)d_ws;
  u16*    W1t   = (u16*)(ws + 0);
  u16*    W2t   = (u16*)(ws + 49152);
  float*  xyz1q = (float*)(ws + 81920);       // alias of kw region
  KW*     kw    = (KW*)(ws + 81920);
  Part*   part  = (Part*)(ws + 1654784);

  repack_w<<<dim3(96), dim3(256), 0, stream>>>(W1, W2, W1t, W2t, in0, xyz1q);
  knn_part<<<dim3(NQ / 256, KSPLIT), dim3(256), 0, stream>>>(xyz1q, in1, part, out);
  knn_merge<<<dim3(NQ / 256), dim3(256), 0, stream>>>(part, kw);
  interp_mlp<<<dim3(NQ / 64), dim3(256), 0, stream>>>(in0, in1, kw, W1t, b1, W2t, b2, out);
}